// Round 1
// 280.307 us; speedup vs baseline: 1.0051x; 1.0051x over previous
//
#include <hip/hip_runtime.h>

// segment_sum: out[g, f] = sum over rows r with batch[r]==g of x[r, f]
// x: (200000, 256) f32 row-major; batch: (200000,) int32 (SORTED); out: (512, 256) f32
//
// Single-kernel plan (fused): one block per segment g.
//  Prologue: waves 0 and 1 each run a 64-ary wave-cooperative lower_bound over
//  the sorted batch array (4 ballot rounds, ~1000 cyc, L2-resident) to find
//  start[g] and start[g+1]. No separate bounds kernel, no workspace.
//  Main loop: rows [r0, r1) streamed branch-free: 4 waves interleave rows,
//  16B/lane float4 loads, unroll x4 (4 loads in flight per wave). Cross-wave
//  partials reduced through 4KB LDS; out[g] written exactly once (empty
//  segments write zeros) -> no memset, no atomics.

#define FEAT 256
#define F4   (FEAT / 4)   // 64 float4 per row == one wave-load per row
#define NSEG 512

// Wave-cooperative lower_bound: first index i in [0,n) with batch[i] >= target
// (returns n if none). All 64 lanes of the wave must be active. 64-ary search:
// each round shrinks the range by ~64x via one ballot. ~4 rounds for n=200000.
__device__ __forceinline__ int lower_bound_wave(const int* __restrict__ batch,
                                                int n, int target, int lane) {
    int lo = 0, len = n;
    while (len > 64) {
        int step = len >> 6;                  // len/64 >= 1
        int q    = lo + lane * step;          // q <= lo + 63*(len/64) < lo+len <= n
        unsigned long long m = __ballot(batch[q] < target);
        int c = __popcll(m);                  // wave-uniform
        if (c == 0) return lo;                // batch[lo] >= target already
        int nlo = lo + (c - 1) * step + 1;    // last "true" probe + 1
        int nhi = (c < 64) ? (lo + c * step)  // first "false" probe
                           : (lo + len);
        lo  = nlo;
        len = nhi - nlo;
    }
    if (len > 0) {
        bool cond = (lane < len) && (batch[lo + lane] < target);
        lo += __popcll(__ballot(cond));
    }
    return lo;
}

__global__ __launch_bounds__(256) void GraphAddPooling_39539468927441_kernel(
    const float* __restrict__ x, const int* __restrict__ batch,
    float* __restrict__ out, int n)
{
    const int g    = blockIdx.x;          // segment id == output row
    const int lane = threadIdx.x & 63;    // float4 column group within row
    const int wave = threadIdx.x >> 6;    // 0..3, interleaved over rows

    __shared__ int sb[2];
    if (wave < 2) {
        int b = lower_bound_wave(batch, n, g + wave, lane);
        if (lane == 0) sb[wave] = b;
    }
    __syncthreads();
    const int r0 = sb[0];
    const int r1 = sb[1];

    const float4* __restrict__ x4 = (const float4*)x;

    float4 a0 = make_float4(0.f, 0.f, 0.f, 0.f);
    float4 a1 = a0, a2 = a0, a3 = a0;

    int r = r0 + wave;
    // Unroll x4: rows r, r+4, r+8, r+12 (wave stride 4, block covers all rows).
    // All 4 loads issue before any accumulate -> 4 memory ops in flight/wave.
    for (; r + 12 < r1; r += 16) {
        float4 v0 = x4[(size_t)r        * F4 + lane];
        float4 v1 = x4[(size_t)(r + 4)  * F4 + lane];
        float4 v2 = x4[(size_t)(r + 8)  * F4 + lane];
        float4 v3 = x4[(size_t)(r + 12) * F4 + lane];
        a0.x += v0.x; a0.y += v0.y; a0.z += v0.z; a0.w += v0.w;
        a1.x += v1.x; a1.y += v1.y; a1.z += v1.z; a1.w += v1.w;
        a2.x += v2.x; a2.y += v2.y; a2.z += v2.z; a2.w += v2.w;
        a3.x += v3.x; a3.y += v3.y; a3.z += v3.z; a3.w += v3.w;
    }
    for (; r < r1; r += 4) {
        float4 v = x4[(size_t)r * F4 + lane];
        a0.x += v.x; a0.y += v.y; a0.z += v.z; a0.w += v.w;
    }
    a0.x += a1.x + a2.x + a3.x;
    a0.y += a1.y + a2.y + a3.y;
    a0.z += a1.z + a2.z + a3.z;
    a0.w += a1.w + a2.w + a3.w;

    // Cross-wave reduction: 4 partials per (lane) column.
    __shared__ float4 red[4][F4];   // 4 KB
    red[wave][lane] = a0;
    __syncthreads();
    if (wave == 0) {
        float4 s = red[0][lane];
        float4 b = red[1][lane], c = red[2][lane], d = red[3][lane];
        s.x += b.x + c.x + d.x;
        s.y += b.y + c.y + d.y;
        s.z += b.z + c.z + d.z;
        s.w += b.w + c.w + d.w;
        ((float4*)out)[(size_t)g * F4 + lane] = s;
    }
}

extern "C" void kernel_launch(void* const* d_in, const int* in_sizes, int n_in,
                              void* d_out, int out_size, void* d_ws, size_t ws_size,
                              hipStream_t stream) {
    const float* x     = (const float*)d_in[0];
    const int*   batch = (const int*)d_in[1];
    float*       out   = (float*)d_out;

    const int n_rows = in_sizes[1];      // 200000

    GraphAddPooling_39539468927441_kernel<<<NSEG, 256, 0, stream>>>(x, batch, out, n_rows);
}